// Round 9
// baseline (125.892 us; speedup 1.0000x reference)
//
#include <hip/hip_runtime.h>
#include <math.h>

#define BD 8
#define SD 1024
#define ID 64
#define OD 128
#define NBD 6
#define NKG 2          // s per nk block

// ---- prep: P2[(j*6+g)*128+i] = P[i,j,g] ; MT/RT transposed weights ---------
__global__ __launch_bounds__(256) void prep_kernel(
    const float* __restrict__ P, const float* __restrict__ M,
    const float* __restrict__ resW,
    float* __restrict__ P2, float* __restrict__ MT, float* __restrict__ RT)
{
    const int idx = blockIdx.x * 256 + threadIdx.x;
    const int NP = OD * OD * NBD;                  // 98304
    if (idx < NP) {
        const int i = idx / (OD * NBD);
        const int r = idx - i * (OD * NBD);        // j*6+g
        P2[r * OD + i] = P[idx];
    } else if (idx < NP + OD * ID) {
        const int k = idx - NP;
        const int i = k / ID, j = k - i * ID;
        MT[j * OD + i] = M[k];
    } else if (idx < NP + 2 * OD * ID) {
        const int k = idx - NP - OD * ID;
        const int i = k / ID, j = k - i * ID;
        RT[j * OD + i] = resW[k];
    }
}

// ---- Kernel A: proj + LN, j split across waves for 8-wave/SIMD occupancy ----
// 512 threads: i = t&127, mj = t>>7: mat = mj&1, jh = mj>>1. w[32] per thread.
__global__ __launch_bounds__(512, 8) void ln_kernel(
    const float* __restrict__ seq,    // (8,1024,64)
    const float* __restrict__ MT,     // (64,128) [j][i]
    const float* __restrict__ RT,     // (64,128) [j][i]
    const float* __restrict__ gamma,
    const float* __restrict__ beta,
    float* __restrict__ xn_g,         // (1024,128,8) [s][j][b]
    float* __restrict__ out)          // (8,1024,128) gets residual
{
    const int t   = threadIdx.x;
    const int s   = blockIdx.x;
    const int i   = t & 127;
    const int mj  = t >> 7;           // wave-uniform
    const int mat = mj & 1;
    const int jh  = mj >> 1;

    __shared__ float part[2][OD][BD + 1];   // jh=1 partials, padded
    __shared__ float red[2][16];

    // 32 weights (half-row), coalesced: lane i reads WT[(jh*32+j)*128 + i]
    float w[32];
    {
        const float* __restrict__ WT = (mat ? RT : MT) + jh * 32 * OD + i;
        #pragma unroll
        for (int j = 0; j < 32; ++j) w[j] = WT[j * OD];
    }

    // partial dots over 32 j; x addresses wave-uniform -> s_load broadcast
    float acc[BD];
    #pragma unroll
    for (int b = 0; b < BD; ++b) {
        const float* __restrict__ xp = &seq[(b * SD + s) * ID + jh * 32];
        float a0 = 0.f, a1 = 0.f;
        #pragma unroll
        for (int j = 0; j < 32; j += 2) {
            a0 = fmaf(xp[j],     w[j],     a0);
            a1 = fmaf(xp[j + 1], w[j + 1], a1);
        }
        acc[b] = a0 + a1;
    }

    if (jh == 1) {
        #pragma unroll
        for (int b = 0; b < BD; ++b) part[mat][i][b] = acc[b];
    }
    __syncthreads();

    if (jh == 0) {
        #pragma unroll
        for (int b = 0; b < BD; ++b) acc[b] += part[mat][i][b];
    }

    // LN stats: waves 0,1 (mat0 jh0) reduce over 64 lanes then combine
    if (jh == 0 && mat == 0) {
        float sum[BD], ssq[BD];
        #pragma unroll
        for (int b = 0; b < BD; ++b) { sum[b] = acc[b]; ssq[b] = acc[b] * acc[b]; }
        #pragma unroll
        for (int m = 1; m < 64; m <<= 1) {
            #pragma unroll
            for (int b = 0; b < BD; ++b) {
                sum[b] += __shfl_xor(sum[b], m, 64);
                ssq[b] += __shfl_xor(ssq[b], m, 64);
            }
        }
        if ((t & 63) == 0) {
            const int wv = t >> 6;     // 0 or 1
            #pragma unroll
            for (int b = 0; b < BD; ++b) {
                red[wv][b]     = sum[b];
                red[wv][8 + b] = ssq[b];
            }
        }
    }
    __syncthreads();

    if (jh == 0) {
        if (mat == 0) {
            const float gm = gamma[i];
            const float bt = beta[i];
            float xn[BD];
            #pragma unroll
            for (int b = 0; b < BD; ++b) {
                const float sm = red[0][b] + red[1][b];
                const float sq = red[0][8 + b] + red[1][8 + b];
                const float mu = sm * (1.0f / OD);
                const float vr = sq * (1.0f / OD) - mu * mu;
                const float rstd = rsqrtf(vr + 1e-5f);
                xn[b] = (acc[b] - mu) * rstd * gm + bt;
            }
            float* __restrict__ dst = &xn_g[(s * OD + i) * BD];
            *(float4*)&dst[0] = make_float4(xn[0], xn[1], xn[2], xn[3]);
            *(float4*)&dst[4] = make_float4(xn[4], xn[5], xn[6], xn[7]);
        } else {
            #pragma unroll
            for (int b = 0; b < BD; ++b)
                out[(b * SD + s) * OD + i] = acc[b];
        }
    }
}

// ---- Kernel B: Nk, out += Nk -----------------------------------------------
// 512 threads = 8 jq waves (16 j each); NKG=2 s in registers; grid (512,2)
// -> 1024 blocks = 4 blocks/CU x 8 waves = 32 waves/CU (VGPR <= 64).
__global__ __launch_bounds__(512, 8) void nk_kernel(
    const float* __restrict__ P2,     // [j][g][i]
    const float* __restrict__ xn_g,   // (1024,128,8) [s][j][b]
    float* __restrict__ out)          // (8,1024,128)
{
    const int s0 = blockIdx.x * NKG;
    const int ih = blockIdx.y;
    const int t  = threadIdx.x;
    const int il = t & 63;
    const int jq = __builtin_amdgcn_readfirstlane(t >> 6);  // 0..7, uniform
    const int i  = ih * 64 + il;

    __shared__ __align__(16) float xn[NKG][OD][BD];   // 8 KB [ls][j][b]
    __shared__ float stage[8][64][BD + 1];            // 18.4 KB, conflict-free

    // stage xn for the block's 2 s (contiguous, coalesced)
    for (int o = t; o < NKG * OD * BD; o += 512)
        ((float*)xn)[o] = xn_g[s0 * OD * BD + o];
    __syncthreads();

    float acc[NKG][BD];
    #pragma unroll
    for (int ls = 0; ls < NKG; ++ls)
        #pragma unroll
        for (int b = 0; b < BD; ++b) acc[ls][b] = 0.f;

    const float pbase = (float)(i * (OD * NBD) + 2);  // exact int in f32
    const int j0 = jq * 16;

    #pragma unroll 2
    for (int j = 0; j < 16; ++j) {
        const int jj = j0 + j;
        const float* __restrict__ Pp = &P2[(jj * NBD) * OD + i];  // coalesced
        float Pv[NBD], rp[NBD];
        #pragma unroll
        for (int g = 0; g < NBD; ++g) {
            Pv[g] = Pp[g * OD];
            rp[g] = __builtin_amdgcn_rcpf(pbase + (float)(jj * NBD + g)); // /2 s
        }
        #pragma unroll
        for (int ls = 0; ls < NKG; ++ls) {
            const float sf = (float)(s0 + ls);
            float wsum = 0.f;
            #pragma unroll
            for (int g = 0; g < NBD; ++g) {
                const float fr = __builtin_amdgcn_fractf(sf * rp[g]);  // revolutions
                wsum = fmaf(Pv[g], __builtin_amdgcn_cosf(fr), wsum);   // cos(2*pi*fr)
            }
            const float4 xlo = *(const float4*)&xn[ls][jj][0];  // LDS broadcast
            const float4 xhi = *(const float4*)&xn[ls][jj][4];
            acc[ls][0] = fmaf(xlo.x, wsum, acc[ls][0]);
            acc[ls][1] = fmaf(xlo.y, wsum, acc[ls][1]);
            acc[ls][2] = fmaf(xlo.z, wsum, acc[ls][2]);
            acc[ls][3] = fmaf(xlo.w, wsum, acc[ls][3]);
            acc[ls][4] = fmaf(xhi.x, wsum, acc[ls][4]);
            acc[ls][5] = fmaf(xhi.y, wsum, acc[ls][5]);
            acc[ls][6] = fmaf(xhi.z, wsum, acc[ls][6]);
            acc[ls][7] = fmaf(xhi.w, wsum, acc[ls][7]);
        }
    }

    // ---- reduce 8 jq partials per s, out += Nk ----
    #pragma unroll
    for (int ls = 0; ls < NKG; ++ls) {
        __syncthreads();
        #pragma unroll
        for (int b = 0; b < BD; ++b) stage[jq][il][b] = acc[ls][b];
        __syncthreads();
        {
            const int ii = t & 63;     // coalesced store dimension
            const int b  = t >> 6;
            float v = 0.f;
            #pragma unroll
            for (int q = 0; q < 8; ++q) v += stage[q][ii][b];
            out[(b * SD + (s0 + ls)) * OD + ih * 64 + ii] += v;
        }
    }
}

extern "C" void kernel_launch(void* const* d_in, const int* in_sizes, int n_in,
                              void* d_out, int out_size, void* d_ws, size_t ws_size,
                              hipStream_t stream) {
    const float* seq   = (const float*)d_in[0];
    const float* M     = (const float*)d_in[1];
    const float* P     = (const float*)d_in[2];
    const float* resW  = (const float*)d_in[3];
    const float* gamma = (const float*)d_in[4];
    const float* beta  = (const float*)d_in[5];
    float* out = (float*)d_out;

    float* xn_g = (float*)d_ws;                    // 4 MB
    float* P2   = xn_g + SD * OD * BD;             // 384 KB
    float* MT   = P2 + OD * OD * NBD;              // 32 KB
    float* RT   = MT + OD * ID;                    // 32 KB

    const int prep_elems = OD * OD * NBD + 2 * OD * ID;  // 114688
    prep_kernel<<<dim3((prep_elems + 255) / 256), dim3(256), 0, stream>>>(
        P, M, resW, P2, MT, RT);
    ln_kernel<<<dim3(SD), dim3(512), 0, stream>>>(seq, MT, RT, gamma, beta,
                                                  xn_g, out);
    nk_kernel<<<dim3(SD / NKG, 2), dim3(512), 0, stream>>>(P2, xn_g, out);
}

// Round 10
// 52.265 us; speedup vs baseline: 2.4087x; 2.4087x over previous
//
#include <hip/hip_runtime.h>
#include <math.h>

#define BD 8
#define SD 1024
#define ID 64
#define OD 128
#define NBD 6
#define NKG 2          // s per nk block

// ---- prep: P2h[(j*128+i)*6+g] = bf16(P[i,j,g]) ; MT/RT transposed weights ---
__global__ __launch_bounds__(256) void prep_kernel(
    const float* __restrict__ P, const float* __restrict__ M,
    const float* __restrict__ resW,
    ushort* __restrict__ P2h, float* __restrict__ MT, float* __restrict__ RT)
{
    const int idx = blockIdx.x * 256 + threadIdx.x;
    const int NP = OD * OD * NBD;                  // 98304
    if (idx < NP) {
        const int i = idx / (OD * NBD);
        const int r = idx - i * (OD * NBD);        // j*6+g
        const int j = r / NBD;
        const int g = r - j * NBD;
        union { float f; unsigned u; } cv; cv.f = P[idx];
        // round-to-nearest-even bf16
        const unsigned rnd = (cv.u + 0x7FFFu + ((cv.u >> 16) & 1u)) >> 16;
        P2h[(j * OD + i) * NBD + g] = (ushort)rnd;
    } else if (idx < NP + OD * ID) {
        const int k = idx - NP;
        const int i = k / ID, j = k - i * ID;
        MT[j * OD + i] = M[k];
    } else if (idx < NP + 2 * OD * ID) {
        const int k = idx - NP - OD * ID;
        const int i = k / ID, j = k - i * ID;
        RT[j * OD + i] = resW[k];
    }
}

// ---- Kernel A: weight-stationary proj + LN -> xn_g ; residual -> out -------
// (exact R4 version: 256 threads, w[64] in VGPRs, no min-wave clamp)
__global__ __launch_bounds__(256) void ln_kernel(
    const float* __restrict__ seq,    // (8,1024,64)
    const float* __restrict__ MT,     // (64,128) [j][i]
    const float* __restrict__ RT,     // (64,128) [j][i]
    const float* __restrict__ gamma,
    const float* __restrict__ beta,
    float* __restrict__ xn_g,         // (1024,128,8) [s][j][b]
    float* __restrict__ out)          // (8,1024,128) gets residual
{
    const int t   = threadIdx.x;
    const int s   = blockIdx.x;
    const int i   = t & 127;
    const int mat = t >> 7;           // wave-uniform
    __shared__ float red[2][16];

    float w[ID];
    {
        const float* __restrict__ WT = (mat ? RT : MT) + i;
        #pragma unroll
        for (int j = 0; j < ID; ++j) w[j] = WT[j * OD];   // coalesced
    }
    const float gm = gamma[i];
    const float bt = beta[i];

    float acc[BD];
    #pragma unroll
    for (int b = 0; b < BD; ++b) {
        const float* __restrict__ xp = &seq[(b * SD + s) * ID];  // uniform -> s_load
        float a0 = 0.f, a1 = 0.f;
        #pragma unroll
        for (int j = 0; j < ID; j += 2) {
            a0 = fmaf(xp[j],     w[j],     a0);
            a1 = fmaf(xp[j + 1], w[j + 1], a1);
        }
        acc[b] = a0 + a1;
    }

    if (mat == 0) {
        float sum[BD], ssq[BD];
        #pragma unroll
        for (int b = 0; b < BD; ++b) { sum[b] = acc[b]; ssq[b] = acc[b] * acc[b]; }
        #pragma unroll
        for (int m = 1; m < 64; m <<= 1) {
            #pragma unroll
            for (int b = 0; b < BD; ++b) {
                sum[b] += __shfl_xor(sum[b], m, 64);
                ssq[b] += __shfl_xor(ssq[b], m, 64);
            }
        }
        if ((t & 63) == 0) {
            const int wv = t >> 6;
            #pragma unroll
            for (int b = 0; b < BD; ++b) {
                red[wv][b]     = sum[b];
                red[wv][8 + b] = ssq[b];
            }
        }
    }
    __syncthreads();

    if (mat == 0) {
        float xn[BD];
        #pragma unroll
        for (int b = 0; b < BD; ++b) {
            const float sm = red[0][b] + red[1][b];
            const float sq = red[0][8 + b] + red[1][8 + b];
            const float mu = sm * (1.0f / OD);
            const float vr = sq * (1.0f / OD) - mu * mu;
            const float rstd = rsqrtf(vr + 1e-5f);
            xn[b] = (acc[b] - mu) * rstd * gm + bt;
        }
        float* __restrict__ dst = &xn_g[(s * OD + i) * BD];
        *(float4*)&dst[0] = make_float4(xn[0], xn[1], xn[2], xn[3]);
        *(float4*)&dst[4] = make_float4(xn[4], xn[5], xn[6], xn[7]);
    } else {
        #pragma unroll
        for (int b = 0; b < BD; ++b)
            out[(b * SD + s) * OD + i] = acc[b];
    }
}

// ---- Kernel B: Nk, out += Nk (R4 structure, bf16 P table) ------------------
// 256 threads: il = t&63, jq = t>>6 (4 waves x 32 j). NKG=2 s; xn in LDS.
__global__ __launch_bounds__(256, 4) void nk_kernel(
    const ushort* __restrict__ P2h,   // [j][i][g] bf16
    const float* __restrict__ xn_g,   // (1024,128,8) [s][j][b]
    float* __restrict__ out)          // (8,1024,128)
{
    const int s0 = blockIdx.x * NKG;
    const int ih = blockIdx.y;
    const int t  = threadIdx.x;
    const int il = t & 63;
    const int jq = __builtin_amdgcn_readfirstlane(t >> 6);  // wave id, uniform
    const int i  = ih * 64 + il;

    __shared__ __align__(16) float xn[NKG][OD][BD];   // 8 KB
    __shared__ float stage[4][ID][BD + 1];            // padded, conflict-free

    // stage xn for this block's s-pair (coalesced)
    for (int o = t; o < NKG * OD * BD; o += 256)
        ((float*)xn)[o] = xn_g[s0 * OD * BD + o];
    __syncthreads();

    float acc[NKG][BD];
    #pragma unroll
    for (int ls = 0; ls < NKG; ++ls)
        #pragma unroll
        for (int b = 0; b < BD; ++b) acc[ls][b] = 0.f;

    const float pbase = (float)(i * (OD * NBD) + 2);  // exact int in f32

    #pragma unroll 4
    for (int j = 0; j < 32; ++j) {
        const int jj = (jq << 5) + j;
        // 12 contiguous bytes per lane: 6 bf16 {g0..g5}, fully coalesced
        const unsigned* __restrict__ pp =
            (const unsigned*)(P2h + (jj * OD + i) * NBD);
        const unsigned u0 = pp[0], u1 = pp[1], u2 = pp[2];
        union { unsigned u; float f; } c0, c1, c2, c3, c4, c5;
        c0.u = u0 << 16; c1.u = u0 & 0xFFFF0000u;
        c2.u = u1 << 16; c3.u = u1 & 0xFFFF0000u;
        c4.u = u2 << 16; c5.u = u2 & 0xFFFF0000u;
        const float Pv[NBD] = { c0.f, c1.f, c2.f, c3.f, c4.f, c5.f };

        float rp[NBD];
        #pragma unroll
        for (int g = 0; g < NBD; ++g)
            rp[g] = __builtin_amdgcn_rcpf(pbase + (float)(jj * NBD + g)); // /2 s

        #pragma unroll
        for (int ls = 0; ls < NKG; ++ls) {
            const float sf = (float)(s0 + ls);
            float wsum = 0.f;
            #pragma unroll
            for (int g = 0; g < NBD; ++g) {
                const float fr = __builtin_amdgcn_fractf(sf * rp[g]);  // revolutions
                wsum = fmaf(Pv[g], __builtin_amdgcn_cosf(fr), wsum);   // cos(2*pi*fr)
            }
            const float4 xlo = *(const float4*)&xn[ls][jj][0];  // LDS broadcast
            const float4 xhi = *(const float4*)&xn[ls][jj][4];
            acc[ls][0] = fmaf(xlo.x, wsum, acc[ls][0]);
            acc[ls][1] = fmaf(xlo.y, wsum, acc[ls][1]);
            acc[ls][2] = fmaf(xlo.z, wsum, acc[ls][2]);
            acc[ls][3] = fmaf(xlo.w, wsum, acc[ls][3]);
            acc[ls][4] = fmaf(xhi.x, wsum, acc[ls][4]);
            acc[ls][5] = fmaf(xhi.y, wsum, acc[ls][5]);
            acc[ls][6] = fmaf(xhi.z, wsum, acc[ls][6]);
            acc[ls][7] = fmaf(xhi.w, wsum, acc[ls][7]);
        }
    }

    // ---- reduce 4 jq partials per s, out += Nk ----
    #pragma unroll
    for (int ls = 0; ls < NKG; ++ls) {
        __syncthreads();
        #pragma unroll
        for (int b = 0; b < BD; ++b) stage[jq][il][b] = acc[ls][b];
        __syncthreads();
        #pragma unroll
        for (int o = t; o < ID * BD; o += 256) {
            const int ii = o & 63;
            const int b  = o >> 6;
            const float v = stage[0][ii][b] + stage[1][ii][b]
                          + stage[2][ii][b] + stage[3][ii][b];
            out[(b * SD + (s0 + ls)) * OD + ih * 64 + ii] += v;
        }
    }
}

extern "C" void kernel_launch(void* const* d_in, const int* in_sizes, int n_in,
                              void* d_out, int out_size, void* d_ws, size_t ws_size,
                              hipStream_t stream) {
    const float* seq   = (const float*)d_in[0];
    const float* M     = (const float*)d_in[1];
    const float* P     = (const float*)d_in[2];
    const float* resW  = (const float*)d_in[3];
    const float* gamma = (const float*)d_in[4];
    const float* beta  = (const float*)d_in[5];
    float* out = (float*)d_out;

    float*  xn_g = (float*)d_ws;                        // 4 MB
    ushort* P2h  = (ushort*)(xn_g + SD * OD * BD);      // 192 KB (bf16)
    float*  MT   = (float*)(P2h + OD * OD * NBD);       // 32 KB
    float*  RT   = MT + OD * ID;                        // 32 KB

    const int prep_elems = OD * OD * NBD + 2 * OD * ID; // 114688
    prep_kernel<<<dim3((prep_elems + 255) / 256), dim3(256), 0, stream>>>(
        P, M, resW, P2h, MT, RT);
    ln_kernel<<<dim3(SD), dim3(256), 0, stream>>>(seq, MT, RT, gamma, beta,
                                                  xn_g, out);
    nk_kernel<<<dim3(SD / NKG, 2), dim3(256), 0, stream>>>(P2h, xn_g, out);
}

// Round 11
// 52.108 us; speedup vs baseline: 2.4160x; 1.0030x over previous
//
#include <hip/hip_runtime.h>
#include <math.h>

#define BD 8
#define SD 1024
#define ID 64
#define OD 128
#define NBD 6
#define LS 32               // s per wgen recurrence tile

// ---- prep: P3[g][j][i] = P[i][j][g] ; MT/RT transposed weights --------------
__global__ __launch_bounds__(256) void prep_kernel(
    const float* __restrict__ P, const float* __restrict__ M,
    const float* __restrict__ resW,
    float* __restrict__ P3, float* __restrict__ MT, float* __restrict__ RT)
{
    const int idx = blockIdx.x * 256 + threadIdx.x;
    const int NP = OD * OD * NBD;                  // 98304
    if (idx < NP) {
        // write-coalesced: idx = g*16384 + j*128 + i
        const int i = idx & 127;
        const int j = (idx >> 7) & 127;
        const int g = idx >> 14;
        P3[idx] = P[(i * OD + j) * NBD + g];
    } else if (idx < NP + OD * ID) {
        const int k = idx - NP;
        const int i = k / ID, j = k - i * ID;
        MT[j * OD + i] = M[k];
    } else if (idx < NP + 2 * OD * ID) {
        const int k = idx - NP - OD * ID;
        const int i = k / ID, j = k - i * ID;
        RT[j * OD + i] = resW[k];
    }
}

// ---- Kernel A: weight-stationary proj + LN (exact R4 known-good) -----------
__global__ __launch_bounds__(256) void ln_kernel(
    const float* __restrict__ seq,    // (8,1024,64)
    const float* __restrict__ MT,     // (64,128) [j][i]
    const float* __restrict__ RT,     // (64,128) [j][i]
    const float* __restrict__ gamma,
    const float* __restrict__ beta,
    float* __restrict__ xn_g,         // (1024,128,8) [s][j][b]
    float* __restrict__ out)          // (8,1024,128) gets residual
{
    const int t   = threadIdx.x;
    const int s   = blockIdx.x;
    const int i   = t & 127;
    const int mat = t >> 7;           // wave-uniform
    __shared__ float red[2][16];

    float w[ID];
    {
        const float* __restrict__ WT = (mat ? RT : MT) + i;
        #pragma unroll
        for (int j = 0; j < ID; ++j) w[j] = WT[j * OD];   // coalesced
    }
    const float gm = gamma[i];
    const float bt = beta[i];

    float acc[BD];
    #pragma unroll
    for (int b = 0; b < BD; ++b) {
        const float* __restrict__ xp = &seq[(b * SD + s) * ID];  // uniform -> s_load
        float a0 = 0.f, a1 = 0.f;
        #pragma unroll
        for (int j = 0; j < ID; j += 2) {
            a0 = fmaf(xp[j],     w[j],     a0);
            a1 = fmaf(xp[j + 1], w[j + 1], a1);
        }
        acc[b] = a0 + a1;
    }

    if (mat == 0) {
        float sum[BD], ssq[BD];
        #pragma unroll
        for (int b = 0; b < BD; ++b) { sum[b] = acc[b]; ssq[b] = acc[b] * acc[b]; }
        #pragma unroll
        for (int m = 1; m < 64; m <<= 1) {
            #pragma unroll
            for (int b = 0; b < BD; ++b) {
                sum[b] += __shfl_xor(sum[b], m, 64);
                ssq[b] += __shfl_xor(ssq[b], m, 64);
            }
        }
        if ((t & 63) == 0) {
            const int wv = t >> 6;
            #pragma unroll
            for (int b = 0; b < BD; ++b) {
                red[wv][b]     = sum[b];
                red[wv][8 + b] = ssq[b];
            }
        }
    }
    __syncthreads();

    if (mat == 0) {
        float xn[BD];
        #pragma unroll
        for (int b = 0; b < BD; ++b) {
            const float sm = red[0][b] + red[1][b];
            const float sq = red[0][8 + b] + red[1][8 + b];
            const float mu = sm * (1.0f / OD);
            const float vr = sq * (1.0f / OD) - mu * mu;
            const float rstd = rsqrtf(vr + 1e-5f);
            xn[b] = (acc[b] - mu) * rstd * gm + bt;
        }
        float* __restrict__ dst = &xn_g[(s * OD + i) * BD];
        *(float4*)&dst[0] = make_float4(xn[0], xn[1], xn[2], xn[3]);
        *(float4*)&dst[4] = make_float4(xn[4], xn[5], xn[6], xn[7]);
    } else {
        #pragma unroll
        for (int b = 0; b < BD; ++b)
            out[(b * SD + s) * OD + i] = acc[b];
    }
}

// ---- wgen: W[s][j][i] = bf16( sum_g P[i,j,g]*cos(2*pi*s/p) ) ---------------
// Chebyshev recurrence over s: 1 FMA per (s,g) instead of rcp+fract+cos.
// thread = (i, j, s-tile of LS); coalesced stores (lanes i-consecutive).
__global__ __launch_bounds__(256) void wgen_kernel(
    const float* __restrict__ P3,     // [g][j][i]
    ushort* __restrict__ Wt)          // (1024,128,128) bf16 [s][j][i]
{
    const int idx = blockIdx.x * 256 + threadIdx.x;
    const int i  = idx & 127;
    const int j  = (idx >> 7) & 127;
    const int st = idx >> 14;         // 0..31
    const int s0 = st * LS;

    const float pb  = (float)(i * (OD * NBD) + j * NBD + 2);  // period base
    const float fs0 = (float)s0;
    float Pv[NBD], kk[NBD], c0[NBD], c1[NBD];
    #pragma unroll
    for (int g = 0; g < NBD; ++g) {
        Pv[g] = P3[g * (OD * OD) + j * OD + i];               // coalesced
        const float rp = __builtin_amdgcn_rcpf(pb + (float)g);
        // cos builtin takes revolutions; rp <= 0.5 so no fract needed for theta
        kk[g] = 2.0f * __builtin_amdgcn_cosf(rp);
        c1[g] = __builtin_amdgcn_cosf(__builtin_amdgcn_fractf(fs0 * rp));
        c0[g] = __builtin_amdgcn_cosf(__builtin_amdgcn_fractf((fs0 - 1.0f) * rp));
    }

    ushort* __restrict__ wp = Wt + ((s0 * OD + j) * OD + i);
    #pragma unroll 4
    for (int ss = 0; ss < LS; ++ss) {
        float w = 0.f;
        #pragma unroll
        for (int g = 0; g < NBD; ++g) w = fmaf(Pv[g], c1[g], w);
        union { float f; unsigned u; } cv; cv.f = w;
        const unsigned r = (cv.u + 0x7FFFu + ((cv.u >> 16) & 1u)) >> 16; // RNE bf16
        wp[ss * (OD * OD)] = (ushort)r;      // 128B/wave contiguous
        #pragma unroll
        for (int g = 0; g < NBD; ++g) {
            const float cn = fmaf(kk[g], c1[g], -c0[g]);   // Chebyshev step
            c0[g] = c1[g]; c1[g] = cn;
        }
    }
}

// ---- apply: out[b,s,i] += sum_j xn[b,s,j] * W[s,i,j] -----------------------
// block = s; 512 threads: il=t&63 (i-pair 2il,2il+1), wq=(t>>6)&3 (j-quarter),
// bh=t>>8 (b-half). W read as uint (2 bf16), coalesced; xn via uniform s_load.
__global__ __launch_bounds__(512, 4) void apply_kernel(
    const unsigned int* __restrict__ W32,  // Wt viewed as uint pairs
    const float* __restrict__ xn_g,        // (1024,128,8) [s][j][b]
    float* __restrict__ out)               // (8,1024,128)
{
    const int s  = blockIdx.x;
    const int t  = threadIdx.x;
    const int il = t & 63;
    const int wq = __builtin_amdgcn_readfirstlane((t >> 6) & 3);
    const int bh = __builtin_amdgcn_readfirstlane(t >> 8);

    __shared__ float stage[4][2][ID * 9];   // [wq][bh][il*9 + h*4 + c], padded

    float acc[2][4];
    #pragma unroll
    for (int h = 0; h < 2; ++h)
        #pragma unroll
        for (int c = 0; c < 4; ++c) acc[h][c] = 0.f;

    const unsigned int* __restrict__ wrow = W32 + s * (OD * ID);   // 32 KB slice
    const float* __restrict__ xrow = xn_g + (s * OD) * BD + bh * 4;

    #pragma unroll 4
    for (int j = 0; j < 32; ++j) {
        const int jj = (wq << 5) + j;
        const unsigned int u = wrow[jj * ID + il];     // coalesced dword
        union { unsigned u; float f; } lo, hi;
        lo.u = u << 16;            // i = 2*il
        hi.u = u & 0xFFFF0000u;    // i = 2*il+1
        const float4 xb = *(const float4*)&xrow[jj * BD];  // uniform -> s_load
        acc[0][0] = fmaf(lo.f, xb.x, acc[0][0]);
        acc[0][1] = fmaf(lo.f, xb.y, acc[0][1]);
        acc[0][2] = fmaf(lo.f, xb.z, acc[0][2]);
        acc[0][3] = fmaf(lo.f, xb.w, acc[0][3]);
        acc[1][0] = fmaf(hi.f, xb.x, acc[1][0]);
        acc[1][1] = fmaf(hi.f, xb.y, acc[1][1]);
        acc[1][2] = fmaf(hi.f, xb.z, acc[1][2]);
        acc[1][3] = fmaf(hi.f, xb.w, acc[1][3]);
    }

    {
        float* __restrict__ st0 = &stage[wq][bh][il * 9];
        #pragma unroll
        for (int h = 0; h < 2; ++h)
            #pragma unroll
            for (int c = 0; c < 4; ++c) st0[h * 4 + c] = acc[h][c];
    }
    __syncthreads();

    for (int o = t; o < OD * BD; o += 512) {   // 1024 outputs, coalesced in i
        const int b   = o >> 7;
        const int i   = o & 127;
        const int il2 = i >> 1, h = i & 1;
        const int bh2 = b >> 2, c = b & 3;
        const int off = il2 * 9 + h * 4 + c;
        const float v = stage[0][bh2][off] + stage[1][bh2][off]
                      + stage[2][bh2][off] + stage[3][bh2][off];
        out[(b * SD + s) * OD + i] += v;
    }
}

extern "C" void kernel_launch(void* const* d_in, const int* in_sizes, int n_in,
                              void* d_out, int out_size, void* d_ws, size_t ws_size,
                              hipStream_t stream) {
    const float* seq   = (const float*)d_in[0];
    const float* M     = (const float*)d_in[1];
    const float* P     = (const float*)d_in[2];
    const float* resW  = (const float*)d_in[3];
    const float* gamma = (const float*)d_in[4];
    const float* beta  = (const float*)d_in[5];
    float* out = (float*)d_out;

    float*  xn_g = (float*)d_ws;                        // 4 MB
    float*  P3   = xn_g + SD * OD * BD;                 // 384 KB
    float*  MT   = P3 + OD * OD * NBD;                  // 32 KB
    float*  RT   = MT + OD * ID;                        // 32 KB
    ushort* Wt   = (ushort*)(RT + OD * ID);             // 33.5 MB bf16

    const int prep_elems = OD * OD * NBD + 2 * OD * ID; // 114688
    prep_kernel<<<dim3((prep_elems + 255) / 256), dim3(256), 0, stream>>>(
        P, M, resW, P3, MT, RT);
    ln_kernel<<<dim3(SD), dim3(256), 0, stream>>>(seq, MT, RT, gamma, beta,
                                                  xn_g, out);
    wgen_kernel<<<dim3((OD * OD * (SD / LS)) / 256), dim3(256), 0, stream>>>(P3, Wt);
    apply_kernel<<<dim3(SD), dim3(512), 0, stream>>>(
        (const unsigned int*)Wt, xn_g, out);
}

// Round 12
// 36.857 us; speedup vs baseline: 3.4157x; 1.4138x over previous
//
#include <hip/hip_runtime.h>
#include <math.h>

#define BD 8
#define SD 1024
#define ID 64
#define OD 128
#define NBD 6
#define TI 8            // i-tile per block
#define SCH 32          // s-chunk per block (Chebyshev re-init interval)
#define SS 8            // s per super-step (one MFMA wave each)
#define WPAD 136        // padded LDS row length in bf16 elems (+8 -> 4-bank skew)

typedef short bf16x8 __attribute__((ext_vector_type(8)));
typedef float f32x4 __attribute__((ext_vector_type(4)));

__device__ __forceinline__ ushort rne_bf16(float f) {
    union { float f; unsigned u; } cv; cv.f = f;
    return (ushort)((cv.u + 0x7FFFu + ((cv.u >> 16) & 1u)) >> 16);
}

// ---- prep: P4[i][g][j] = P[i][j][g]; MT/RT transposed weights --------------
__global__ __launch_bounds__(256) void prep_kernel(
    const float* __restrict__ P, const float* __restrict__ M,
    const float* __restrict__ resW,
    float* __restrict__ P4, float* __restrict__ MT, float* __restrict__ RT)
{
    const int idx = blockIdx.x * 256 + threadIdx.x;
    const int NP = OD * OD * NBD;                  // 98304
    if (idx < NP) {
        const int j = idx & 127;
        const int r = idx >> 7;        // i*6+g
        const int g = r % NBD;
        const int i = r / NBD;
        P4[idx] = P[(i * OD + j) * NBD + g];       // write-coalesced
    } else if (idx < NP + OD * ID) {
        const int k = idx - NP;
        const int i = k / ID, j = k - i * ID;
        MT[j * OD + i] = M[k];
    } else if (idx < NP + 2 * OD * ID) {
        const int k = idx - NP - OD * ID;
        const int i = k / ID, j = k - i * ID;
        RT[j * OD + i] = resW[k];
    }
}

// ---- Kernel A: weight-stationary proj + LN -> xnT (bf16); residual -> out --
__global__ __launch_bounds__(256) void ln_kernel(
    const float* __restrict__ seq,    // (8,1024,64)
    const float* __restrict__ MT,     // (64,128) [j][i]
    const float* __restrict__ RT,     // (64,128) [j][i]
    const float* __restrict__ gamma,
    const float* __restrict__ beta,
    ushort* __restrict__ xnT,         // (1024,8,128) bf16 [s][b][j]
    float* __restrict__ out)          // (8,1024,128) gets residual
{
    const int t   = threadIdx.x;
    const int s   = blockIdx.x;
    const int i   = t & 127;
    const int mat = t >> 7;           // wave-uniform
    __shared__ float red[2][16];

    float w[ID];
    {
        const float* __restrict__ WT = (mat ? RT : MT) + i;
        #pragma unroll
        for (int j = 0; j < ID; ++j) w[j] = WT[j * OD];   // coalesced
    }
    const float gm = gamma[i];
    const float bt = beta[i];

    float acc[BD];
    #pragma unroll
    for (int b = 0; b < BD; ++b) {
        const float* __restrict__ xp = &seq[(b * SD + s) * ID];  // uniform -> s_load
        float a0 = 0.f, a1 = 0.f;
        #pragma unroll
        for (int j = 0; j < ID; j += 2) {
            a0 = fmaf(xp[j],     w[j],     a0);
            a1 = fmaf(xp[j + 1], w[j + 1], a1);
        }
        acc[b] = a0 + a1;
    }

    if (mat == 0) {
        float sum[BD], ssq[BD];
        #pragma unroll
        for (int b = 0; b < BD; ++b) { sum[b] = acc[b]; ssq[b] = acc[b] * acc[b]; }
        #pragma unroll
        for (int m = 1; m < 64; m <<= 1) {
            #pragma unroll
            for (int b = 0; b < BD; ++b) {
                sum[b] += __shfl_xor(sum[b], m, 64);
                ssq[b] += __shfl_xor(ssq[b], m, 64);
            }
        }
        if ((t & 63) == 0) {
            const int wv = t >> 6;
            #pragma unroll
            for (int b = 0; b < BD; ++b) {
                red[wv][b]     = sum[b];
                red[wv][8 + b] = ssq[b];
            }
        }
    }
    __syncthreads();

    if (mat == 0) {
        #pragma unroll
        for (int b = 0; b < BD; ++b) {
            const float sm = red[0][b] + red[1][b];
            const float sq = red[0][8 + b] + red[1][8 + b];
            const float mu = sm * (1.0f / OD);
            const float vr = sq * (1.0f / OD) - mu * mu;
            const float rstd = rsqrtf(vr + 1e-5f);
            const float xv = (acc[b] - mu) * rstd * gm + bt;
            xnT[(s * BD + b) * OD + i] = rne_bf16(xv);   // coalesced b16 stores
        }
    } else {
        #pragma unroll
        for (int b = 0; b < BD; ++b)
            out[(b * SD + s) * OD + i] = acc[b];
    }
}

// ---- Kernel B: fused Chebyshev W-gen + MFMA contraction, out += Nk ---------
// grid (32 s-chunks, 16 i-tiles), 512 threads.
// Thread states: (i = t>>6, j in {t&63, 64+(t&63)}) x 6 g -> 12 Chebyshev recurrences.
// Super-step: phase1 gen W[8s][8i][128j] bf16 in LDS; phase2 wave ss does
// 4x mfma_f32_16x16x32_bf16 (A=xn[b][j], B=W^T) and RMWs out.
__global__ __launch_bounds__(512, 4) void nk_kernel(
    const float* __restrict__ P4,     // [i][g][j]
    const ushort* __restrict__ xnT,   // [s][b][j] bf16
    float* __restrict__ out)          // (8,1024,128)
{
    const int sc = blockIdx.x;        // s in [sc*SCH, sc*SCH+SCH)
    const int i0 = blockIdx.y * TI;
    const int t  = threadIdx.x;
    const int il = t >> 6;            // 0..7: local i (phase1) AND wave id (phase2)
    const int jb = t & 63;

    __shared__ ushort Wl[SS][TI][WPAD];   // 17.4 KB
    __shared__ ushort Xl[SS][16][WPAD];   // 34.8 KB (rows 8..15 garbage, unused rows of A)

    // ---- init 12 Chebyshev states ----
    float Pv[12], kk[12], c0[12], c1[12];
    const int ig = i0 + il;
    const float s0f = (float)(sc * SCH);
    #pragma unroll
    for (int p = 0; p < 2; ++p) {
        const int j = jb + p * 64;
        #pragma unroll
        for (int g = 0; g < NBD; ++g) {
            const int q = p * NBD + g;
            Pv[q] = P4[(ig * NBD + g) * OD + j];                  // coalesced
            const float per = (float)(ig * (OD * NBD) + j * NBD + g + 2); // exact int
            const float rp = __builtin_amdgcn_rcpf(per);          // rev per step
            kk[q] = 2.0f * __builtin_amdgcn_cosf(rp);
            c1[q] = __builtin_amdgcn_cosf(__builtin_amdgcn_fractf(s0f * rp));
            c0[q] = __builtin_amdgcn_cosf(__builtin_amdgcn_fractf((s0f - 1.0f) * rp));
        }
    }

    for (int u = 0; u < SCH / SS; ++u) {
        // ---- stage xn tile: 8s x 8b x 128j bf16 = 16 KB ----
        {
            const int sb = sc * SCH + u * SS;
            const uint4* __restrict__ src = (const uint4*)(xnT + sb * (BD * OD));
            #pragma unroll
            for (int r = 0; r < 2; ++r) {
                const int e  = t + 512 * r;       // uint4 index (1024 total)
                const uint4 v = src[e];
                const int eo = e << 3;            // bf16 elem offset
                const int ss = eo >> 10;
                const int b  = (eo >> 7) & 7;
                const int j0 = eo & 127;
                *(uint4*)&Xl[ss][b][j0] = v;
            }
        }
        // ---- phase1: generate W for 8 s (2 FMA per element) ----
        #pragma unroll
        for (int ssi = 0; ssi < SS; ++ssi) {
            #pragma unroll
            for (int p = 0; p < 2; ++p) {
                float w = 0.f;
                #pragma unroll
                for (int g = 0; g < NBD; ++g) w = fmaf(Pv[p * NBD + g], c1[p * NBD + g], w);
                #pragma unroll
                for (int g = 0; g < NBD; ++g) {
                    const int q = p * NBD + g;
                    const float cn = fmaf(kk[q], c1[q], -c0[q]);   // Chebyshev step
                    c0[q] = c1[q]; c1[q] = cn;
                }
                Wl[ssi][il][jb + p * 64] = rne_bf16(w);
            }
        }
        __syncthreads();
        // ---- phase2: wave il handles s = sbase + il ----
        {
            const int l = t & 63;
            f32x4 acc = {0.f, 0.f, 0.f, 0.f};
            #pragma unroll
            for (int m = 0; m < 4; ++m) {
                // A[row=b][k=j]: lane row = l&15, k = m*32 + (l>>4)*8 + e
                const bf16x8 a = *(const bf16x8*)&Xl[il][l & 15][m * 32 + (l >> 4) * 8];
                // B[k=j][col=i] = W[col][k]: read Wl row (l&7) (cols 8..15 dup)
                const bf16x8 b = *(const bf16x8*)&Wl[il][l & 7][m * 32 + (l >> 4) * 8];
                acc = __builtin_amdgcn_mfma_f32_16x16x32_bf16(a, b, acc, 0, 0, 0);
            }
            // C[row][col]: col = l&15, row = (l>>4)*4 + q. Valid: col<8, row<8.
            const int col  = l & 15;
            const int rowg = l >> 4;
            if (col < TI && rowg < 2) {
                const int s = sc * SCH + u * SS + il;
                #pragma unroll
                for (int q = 0; q < 4; ++q) {
                    const int b = rowg * 4 + q;
                    float* __restrict__ dst = &out[(b * SD + s) * OD + i0 + col];
                    *dst += acc[q];
                }
            }
        }
        __syncthreads();   // protect Wl/Xl before next super-step overwrites
    }
}

extern "C" void kernel_launch(void* const* d_in, const int* in_sizes, int n_in,
                              void* d_out, int out_size, void* d_ws, size_t ws_size,
                              hipStream_t stream) {
    const float* seq   = (const float*)d_in[0];
    const float* M     = (const float*)d_in[1];
    const float* P     = (const float*)d_in[2];
    const float* resW  = (const float*)d_in[3];
    const float* gamma = (const float*)d_in[4];
    const float* beta  = (const float*)d_in[5];
    float* out = (float*)d_out;

    ushort* xnT = (ushort*)d_ws;                        // 2 MB bf16 [s][b][j]
    float*  P4  = (float*)(xnT + SD * BD * OD);         // 384 KB
    float*  MT  = P4 + OD * OD * NBD;                   // 32 KB
    float*  RT  = MT + OD * ID;                         // 32 KB

    const int prep_elems = OD * OD * NBD + 2 * OD * ID; // 114688
    prep_kernel<<<dim3((prep_elems + 255) / 256), dim3(256), 0, stream>>>(
        P, M, resW, P4, MT, RT);
    ln_kernel<<<dim3(SD), dim3(256), 0, stream>>>(seq, MT, RT, gamma, beta,
                                                  xnT, out);
    nk_kernel<<<dim3(SD / SCH, OD / TI), dim3(512), 0, stream>>>(P4, xnT, out);
}